// Round 9
// baseline (215.209 us; speedup 1.0000x reference)
//
#include <hip/hip_runtime.h>
#include <hip/hip_bf16.h>

#define B_ 32
#define T_ 2048
#define D_ 1024
#define A_ 128

typedef __attribute__((ext_vector_type(8))) short bf16x8;
typedef __attribute__((ext_vector_type(4))) float f32x4;

static __device__ __forceinline__ unsigned short f2bf(float f) {
  union { float f; unsigned u; } v; v.f = f;
  unsigned r = v.u + 0x7FFFu + ((v.u >> 16) & 1u);
  return (unsigned short)(r >> 16);
}

// packed f32x2 -> bf16x2 (RNE); compiler emits v_cvt_pk_bf16_f32
static __device__ __forceinline__ unsigned cvt2u(float lo, float hi) {
  __hip_bfloat162 h2 = __float22bfloat162_rn(make_float2(lo, hi));
  unsigned u;
  __builtin_memcpy(&u, &h2, 4);
  return u;
}

// lgkm-only barrier: LDS visibility without draining vmcnt (staging + W loads are
// reg-destined; their consumption is enforced by compiler-counted vmcnt at use)
static __device__ __forceinline__ void barrier_lds() {
  asm volatile("s_waitcnt lgkmcnt(0)\n\ts_barrier" ::: "memory");
}

// ---------------- prep: Wt[a][d] = bf16(Ws[d][a]) ----------------
__global__ __launch_bounds__(256) void k_prep(const float* __restrict__ Ws,
                                              unsigned short* __restrict__ Wt) {
  int i = blockIdx.x * 256 + threadIdx.x;  // coalesced write
  int a = i >> 10, d = i & 1023;
  Wt[i] = f2bf(Ws[(size_t)d * A_ + a]);
}

// ---------------- fused: scores -> exp -> weighted x accumulation ----------------
// grid (8, 32): blockIdx.x = t-slice (256 t), blockIdx.y = b. 512 thr (8 waves), 1 blk/CU.
//
// W LOCATION (r4/r6/r7/r8 lesson): hipcc's VGPR budget is 65536/block_size = 128 and
// cannot be raised (amdgpu_waves_per_eu ignored). W-in-registers = 256 KB/block = the
// ENTIRE budget at any block size -> staging always spilled (WRITE_SIZE 238 MB).
// Fix: B-fragments are read from Wt in GLOBAL memory every chunk. Wt = 256 KB, L2-
// resident per XCD (32 blocks re-read it); per-wave per-kt read = 16 full 64B lines,
// zero over-fetch. L2/chunk = 320 KB (~5.8k cyc) < HBM/chunk (~6.4k cyc). Live set
// now ~100 VGPR (stA/stB 64 + misc) < 128: no spills by construction.
//
// 2-deep pipeline: loads for chunk i+2 issue during chunk i (1.5 chunks of flight);
// loop barriers are lgkm-only; stage-writes wait on counted vmcnt, never drain.
#define LDRF 1028  // f32 row stride (4112 B): +16B pad, conflict-free b128/b64
#define LDRB 1032  // bf16 row stride in shorts (2064 B): +16B pad

__global__ __launch_bounds__(512) void k_fused(const float* __restrict__ x,
                                               const unsigned short* __restrict__ Wt,
                                               const float* __restrict__ bs,
                                               const float* __restrict__ us,
                                               float* __restrict__ part,
                                               float* __restrict__ Zp) {
  __shared__ __align__(16) float xb[16 * LDRF];            // 65,792 B (exact f32 chunk)
  __shared__ __align__(16) unsigned short ab[16 * LDRB];   // 33,024 B (bf16 A-buffer)
  __shared__ float sc_part[16 * 8];
  __shared__ float e_lds[16];

  const int tid  = threadIdx.x;
  const int w    = tid >> 6;
  const int lane = tid & 63;
  const int lrow = lane & 15;
  const int g    = lane >> 4;
  const int sub  = blockIdx.x;
  const int b    = blockIdx.y;

  const int a_col = w * 16 + lrow;   // this wave's 16 a-columns
  const float bsv = bs[a_col];
  const float usv = us[a_col];
  const unsigned short* brow = Wt + (size_t)a_col * D_ + g * 8;  // B-frag base (L2)

  // staging: thread owns row srow, 8 float4 at cols scol + q*128 (512B/seg coalesced)
  const int srow = w * 2 + (lane >> 5);
  const int scol = (lane & 31) * 4;
  const float* gx = x + ((size_t)b * T_ + (size_t)sub * 256) * D_;

  float4 stA[8], stB[8];

#define ISSUE(dst, ci)                                                            \
  {                                                                               \
    const float* gp_ = gx + (size_t)(ci) * 16 * D_ + (size_t)srow * D_ + scol;    \
    _Pragma("unroll") for (int q = 0; q < 8; ++q)                                 \
        dst[q] = *(const float4*)(gp_ + q * 128);                                 \
  }

#define WRITE_AB(src)                                                             \
  {                                                                               \
    _Pragma("unroll") for (int q = 0; q < 8; ++q) {                               \
      *(float4*)(&xb[srow * LDRF + scol + q * 128]) = src[q];                     \
      unsigned lo_ = cvt2u(src[q].x, src[q].y);                                   \
      unsigned hi_ = cvt2u(src[q].z, src[q].w);                                   \
      *(uint2*)(&ab[srow * LDRB + scol + q * 128]) = make_uint2(lo_, hi_);        \
    }                                                                             \
  }

// Process the chunk resident in xb/ab: GEMM (A from LDS, B from L2-resident Wt) ->
// score -> e -> accumulate. C layout: col = lane&15 (a), row = g*4 + r (t).
// |score| <= ||us||_1 ~ 9 => expf without max-shift is safe in f32.
#define CHUNK_BODY()                                                              \
  {                                                                               \
    f32x4 accm = (f32x4)0.f;                                                      \
    const unsigned short* arow = ab + lrow * LDRB + g * 8;                        \
    _Pragma("unroll") for (int kt = 0; kt < 32; ++kt) {                           \
      bf16x8 af = *(const bf16x8*)(arow + kt * 32);                               \
      bf16x8 bf = *(const bf16x8*)(brow + kt * 32);                               \
      accm = __builtin_amdgcn_mfma_f32_16x16x32_bf16(af, bf, accm, 0, 0, 0);      \
    }                                                                             \
    _Pragma("unroll") for (int r = 0; r < 4; ++r) {                               \
      float p = usv * tanhf(accm[r] + bsv);                                       \
      _Pragma("unroll") for (int o = 1; o < 16; o <<= 1)                          \
          p += __shfl_xor(p, o, 64);                                              \
      if (lrow == 0) sc_part[(g * 4 + r) * 8 + w] = p;                            \
    }                                                                             \
    barrier_lds();                                                                \
    if (tid < 16) {                                                               \
      float s_ = 0.f;                                                             \
      _Pragma("unroll") for (int ww = 0; ww < 8; ++ww) s_ += sc_part[tid * 8 + ww];\
      e_lds[tid] = expf(s_);                                                      \
    }                                                                             \
    barrier_lds();                                                                \
    const float* xd = xb + tid * 2;                                               \
    _Pragma("unroll") for (int t = 0; t < 16; ++t) {                              \
      const float2 v_ = *(const float2*)(xd + t * LDRF);                          \
      const float ev_ = e_lds[t];                                                 \
      a0 = fmaf(ev_, v_.x, a0);                                                   \
      a1 = fmaf(ev_, v_.y, a1);                                                   \
      zacc += ev_;                                                                \
    }                                                                             \
  }

  float a0 = 0.f, a1 = 0.f, zacc = 0.f;

  // prologue: chunks 0,1 in flight; stage chunk 0 (counted vmcnt: stB stays in flight)
  ISSUE(stA, 0);
  ISSUE(stB, 1);
  __builtin_amdgcn_sched_barrier(0);
  WRITE_AB(stA);
  barrier_lds();

  for (int i = 0; i < 16; i += 2) {
    // ---- even chunk i: LDS holds i, stB = chunk i+1 in flight, stA free ----
    if (i + 2 < 16) ISSUE(stA, i + 2);
    __builtin_amdgcn_sched_barrier(0);
    CHUNK_BODY();            // consume chunk i
    barrier_lds();           // all reads of chunk i complete
    WRITE_AB(stB);           // stage chunk i+1 (counted vmcnt, i+2 stays in flight)
    barrier_lds();

    // ---- odd chunk i+1: LDS holds i+1, stA = chunk i+2 in flight, stB free ----
    if (i + 3 < 16) ISSUE(stB, i + 3);
    __builtin_amdgcn_sched_barrier(0);
    CHUNK_BODY();            // consume chunk i+1
    barrier_lds();
    if (i + 2 < 16) WRITE_AB(stA);  // stage chunk i+2
    barrier_lds();
  }

  float* pp = part + ((size_t)sub * B_ + b) * D_ + tid * 2;
  *(float2*)pp = make_float2(a0, a1);
  if (tid == 0) Zp[b * 8 + sub] = zacc;
#undef ISSUE
#undef WRITE_AB
#undef CHUNK_BODY
}

// ---------------- reduce 8 slice-partials, divide by Z ----------------
__global__ __launch_bounds__(256) void k_reduce(const float* __restrict__ part,
                                                const float* __restrict__ Zp,
                                                float* __restrict__ out) {
  const int i = blockIdx.x * 256 + threadIdx.x;  // 0..32767
  const int b = i >> 10, d = i & 1023;
  float zs = 0.f;
#pragma unroll
  for (int s = 0; s < 8; ++s) zs += Zp[b * 8 + s];
  float acc = 0.f;
#pragma unroll
  for (int s = 0; s < 8; ++s) acc += part[((size_t)s * B_ + b) * D_ + d];
  out[i] = acc / zs;
}

extern "C" void kernel_launch(void* const* d_in, const int* in_sizes, int n_in,
                              void* d_out, int out_size, void* d_ws, size_t ws_size,
                              hipStream_t stream) {
  const float* x  = (const float*)d_in[0];
  const float* Ws = (const float*)d_in[1];
  const float* bs = (const float*)d_in[2];
  const float* us = (const float*)d_in[3];
  float* out = (float*)d_out;

  char* ws = (char*)d_ws;
  unsigned short* Wt = (unsigned short*)ws;                 // 256 KB
  float* part = (float*)(ws + (256 << 10));                 // 1 MB
  float* Zp   = (float*)(ws + (256 << 10) + (1 << 20));     // 1 KB

  k_prep<<<512, 256, 0, stream>>>(Ws, Wt);
  k_fused<<<dim3(8, B_), 512, 0, stream>>>(x, Wt, bs, us, part, Zp);
  k_reduce<<<(B_ * D_) / 256, 256, 0, stream>>>(part, Zp, out);
}

// Round 10
// 80.183 us; speedup vs baseline: 2.6840x; 2.6840x over previous
//
#include <hip/hip_runtime.h>
#include <hip/hip_bf16.h>

#define B_ 32
#define T_ 2048
#define D_ 1024
#define A_ 128

typedef __attribute__((ext_vector_type(8))) short bf16x8;
typedef __attribute__((ext_vector_type(4))) float f32x4;

static __device__ __forceinline__ unsigned short f2bf(float f) {
  union { float f; unsigned u; } v; v.f = f;
  unsigned r = v.u + 0x7FFFu + ((v.u >> 16) & 1u);
  return (unsigned short)(r >> 16);
}

// packed f32x2 -> bf16x2 (RNE); compiler emits v_cvt_pk_bf16_f32
static __device__ __forceinline__ unsigned cvt2u(float lo, float hi) {
  __hip_bfloat162 h2 = __float22bfloat162_rn(make_float2(lo, hi));
  unsigned u;
  __builtin_memcpy(&u, &h2, 4);
  return u;
}

// lgkm-only barrier: LDS visibility without draining vmcnt (st/B loads are
// reg-destined; their consumption is enforced by compiler-counted vmcnt at use)
static __device__ __forceinline__ void barrier_lds() {
  asm volatile("s_waitcnt lgkmcnt(0)\n\ts_barrier" ::: "memory");
}

// ---------------- prep: Wt[a][d] = bf16(Ws[d][a]) ----------------
__global__ __launch_bounds__(256) void k_prep(const float* __restrict__ Ws,
                                              unsigned short* __restrict__ Wt) {
  int i = blockIdx.x * 256 + threadIdx.x;  // coalesced write
  int a = i >> 10, d = i & 1023;
  Wt[i] = f2bf(Ws[(size_t)d * A_ + a]);
}

// ---------------- fused: scores -> exp -> weighted x accumulation ----------------
// grid (8, 32): blockIdx.x = t-slice (256 t), blockIdx.y = b. 512 thr (8 waves), 1 blk/CU.
//
// Register discipline (r4-r9 lessons): hipcc allocates at most 65536 VGPRs per block
// (= 128/thread @ 512thr) regardless of launch_bounds/waves_per_eu. W-in-registers
// (wreg[32] = 128 VGPR) consumed the whole budget -> every variant spilled staging regs
// to scratch (WRITE_SIZE 110-249 MB). Fix: NO wreg — B-fragments stream from Wt in
// global memory (L2-resident: 256 KB, re-read by 32 blocks/XCD; 16 full 64B lines per
// wave per kt, zero over-fetch; r9 confirmed FETCH stays ~ideal). Live set ~70 VGPR:
// st[8]=32 + ~12 B-frags in flight + misc. 1-deep staging only (2-deep = spills).
#define LDRF 1028  // f32 row stride (4112 B): +16B pad, conflict-free b128/b64
#define LDRB 1032  // bf16 row stride in shorts (2064 B): +16B pad

__global__ __launch_bounds__(512) void k_fused(const float* __restrict__ x,
                                               const unsigned short* __restrict__ Wt,
                                               const float* __restrict__ bs,
                                               const float* __restrict__ us,
                                               float* __restrict__ part,
                                               float* __restrict__ Zp) {
  __shared__ __align__(16) float xb[16 * LDRF];            // 65,792 B (exact f32 chunk)
  __shared__ __align__(16) unsigned short ab[16 * LDRB];   // 33,024 B (bf16 A-buffer)
  __shared__ float sc_part[16 * 8];
  __shared__ float e_lds[16];

  const int tid  = threadIdx.x;
  const int w    = tid >> 6;
  const int lane = tid & 63;
  const int lrow = lane & 15;
  const int g    = lane >> 4;
  const int sub  = blockIdx.x;
  const int b    = blockIdx.y;

  const int a_col = w * 16 + lrow;   // this wave's 16 a-columns
  const float bsv = bs[a_col];
  const float usv = us[a_col];
  const unsigned short* brow = Wt + (size_t)a_col * D_ + g * 8;  // B-frag base (L2)

  // staging: thread owns row srow, 8 float4 at cols scol + q*128 (512B/seg coalesced)
  const int srow = w * 2 + (lane >> 5);
  const int scol = (lane & 31) * 4;
  const float* gx = x + ((size_t)b * T_ + (size_t)sub * 256) * D_;

  float4 st[8];

  // prologue: chunk 0 -> regs -> LDS (f32 + bf16)
#pragma unroll
  for (int q = 0; q < 8; ++q)
    st[q] = *(const float4*)(gx + (size_t)srow * D_ + scol + q * 128);
#pragma unroll
  for (int q = 0; q < 8; ++q) {
    *(float4*)(&xb[srow * LDRF + scol + q * 128]) = st[q];
    unsigned lo = cvt2u(st[q].x, st[q].y);
    unsigned hi = cvt2u(st[q].z, st[q].w);
    *(uint2*)(&ab[srow * LDRB + scol + q * 128]) = make_uint2(lo, hi);
  }
  barrier_lds();

  float a0 = 0.f, a1 = 0.f, zacc = 0.f;

  for (int i = 0; i < 16; ++i) {
    // issue next-chunk global loads NOW; they land during this chunk's compute
    if (i < 15) {
      const float* gc = gx + (size_t)(i + 1) * 16 * D_;
#pragma unroll
      for (int q = 0; q < 8; ++q)
        st[q] = *(const float4*)(gc + (size_t)srow * D_ + scol + q * 128);
    }
    __builtin_amdgcn_sched_barrier(0);  // pin load issue above the compute

    // GEMM: z[16 t][16 a-cols of this wave] over K=1024
    // A-frags bf16 from LDS ab; B-frags stream from L2-resident Wt
    f32x4 accm = (f32x4)0.f;
    const unsigned short* arow = ab + lrow * LDRB + g * 8;
#pragma unroll
    for (int kt = 0; kt < 32; ++kt) {
      bf16x8 af = *(const bf16x8*)(arow + kt * 32);
      bf16x8 bf = *(const bf16x8*)(brow + kt * 32);
      accm = __builtin_amdgcn_mfma_f32_16x16x32_bf16(af, bf, accm, 0, 0, 0);
    }

    // per-wave score partial: sum over this wave's 16 a of us*tanh(z+bs)
    // C layout: col = lane&15 (a), row = g*4 + r (t)
#pragma unroll
    for (int r = 0; r < 4; ++r) {
      float p = usv * tanhf(accm[r] + bsv);
#pragma unroll
      for (int o = 1; o < 16; o <<= 1) p += __shfl_xor(p, o, 64);
      if (lrow == 0) sc_part[(g * 4 + r) * 8 + w] = p;
    }
    barrier_lds();

    // |score| <= ||us||_1 ~ 9 => exp without max-shift is safe in f32
    if (tid < 16) {
      float s = 0.f;
#pragma unroll
      for (int ww = 0; ww < 8; ++ww) s += sc_part[tid * 8 + ww];
      e_lds[tid] = expf(s);
    }
    barrier_lds();

    // exact f32 accumulate: thread owns d = 2*tid, 2*tid+1
    const float* xd = xb + tid * 2;
#pragma unroll
    for (int t = 0; t < 16; ++t) {
      const float2 v = *(const float2*)(xd + t * LDRF);
      const float ev = e_lds[t];
      a0 = fmaf(ev, v.x, a0);
      a1 = fmaf(ev, v.y, a1);
      zacc += ev;  // uniform across threads; thread 0 writes
    }
    barrier_lds();  // all xb/ab reads of chunk i complete

    if (i < 15) {
      // stage chunk i+1 (ds_write waits counted vmcnt on its own loads only)
#pragma unroll
      for (int q = 0; q < 8; ++q) {
        *(float4*)(&xb[srow * LDRF + scol + q * 128]) = st[q];
        unsigned lo = cvt2u(st[q].x, st[q].y);
        unsigned hi = cvt2u(st[q].z, st[q].w);
        *(uint2*)(&ab[srow * LDRB + scol + q * 128]) = make_uint2(lo, hi);
      }
      barrier_lds();
    }
  }

  float* pp = part + ((size_t)sub * B_ + b) * D_ + tid * 2;
  *(float2*)pp = make_float2(a0, a1);
  if (tid == 0) Zp[b * 8 + sub] = zacc;
}

// ---------------- reduce 8 slice-partials, divide by Z ----------------
__global__ __launch_bounds__(256) void k_reduce(const float* __restrict__ part,
                                                const float* __restrict__ Zp,
                                                float* __restrict__ out) {
  const int i = blockIdx.x * 256 + threadIdx.x;  // 0..32767
  const int b = i >> 10, d = i & 1023;
  float zs = 0.f;
#pragma unroll
  for (int s = 0; s < 8; ++s) zs += Zp[b * 8 + s];
  float acc = 0.f;
#pragma unroll
  for (int s = 0; s < 8; ++s) acc += part[((size_t)s * B_ + b) * D_ + d];
  out[i] = acc / zs;
}

extern "C" void kernel_launch(void* const* d_in, const int* in_sizes, int n_in,
                              void* d_out, int out_size, void* d_ws, size_t ws_size,
                              hipStream_t stream) {
  const float* x  = (const float*)d_in[0];
  const float* Ws = (const float*)d_in[1];
  const float* bs = (const float*)d_in[2];
  const float* us = (const float*)d_in[3];
  float* out = (float*)d_out;

  char* ws = (char*)d_ws;
  unsigned short* Wt = (unsigned short*)ws;                 // 256 KB
  float* part = (float*)(ws + (256 << 10));                 // 1 MB
  float* Zp   = (float*)(ws + (256 << 10) + (1 << 20));     // 1 KB

  k_prep<<<512, 256, 0, stream>>>(Ws, Wt);
  k_fused<<<dim3(8, B_), 512, 0, stream>>>(x, Wt, bs, us, part, Zp);
  k_reduce<<<(B_ * D_) / 256, 256, 0, stream>>>(part, Zp, out);
}